// Round 1
// baseline (9.599 us; speedup 1.0000x reference)
//
#include <hip/hip_runtime.h>

// LambdaRankLoss_6940667150369
//
// The reference computes:
//   delta_ndcg = zeros_like(ti) * (ideal_dcg / ideal_dcg)   // == zeros (ideal_dcg finite, >0)
//   lambda_ij  = (1 - pij) * sij * delta_ndcg               // == 0
//   per_pair   = where(sij != 0, lambda_ij * pred_diff, 0)  // == 0 (pred_diff finite)
//   loss       = -sum(per_pair) / num_pairs                 // == -0.0
//
// The output is identically zero for all valid inputs (targets in [0,4] =>
// ideal_dcg is a finite positive scalar => ideal_dcg/ideal_dcg == 1.0 with no
// NaN/Inf hazard; predictions are finite => no 0*Inf). So the optimal kernel
// writes a single float 0.0 to d_out. Deterministic, input-independent.

__global__ void LambdaRankLoss_6940667150369_kernel(float* out) {
    out[0] = -0.0f;
}

extern "C" void kernel_launch(void* const* d_in, const int* in_sizes, int n_in,
                              void* d_out, int out_size, void* d_ws, size_t ws_size,
                              hipStream_t stream) {
    (void)d_in; (void)in_sizes; (void)n_in; (void)out_size; (void)d_ws; (void)ws_size;
    LambdaRankLoss_6940667150369_kernel<<<1, 1, 0, stream>>>((float*)d_out);
}